// Round 6
// baseline (60.645 us; speedup 1.0000x reference)
//
#include <hip/hip_runtime.h>
#include <math.h>

// LSTM autoencoder, single timestep, h0=c0=0.
// => whh matrices unused; f-gate unused (f*c0 == 0).
// 7 plain kernels (graph-captured), 512-thread blocks, column-split rows.
// NEW vs R5: e1l0 (100.7 MB) and out_w (33.6 MB) weight loads are
// NON-TEMPORAL so they don't allocate in cache; the remaining ~126 MB of
// weights then fits entirely in the 256 MB Infinity Cache across replays.

typedef float v4f __attribute__((ext_vector_type(4)));

__device__ __forceinline__ float sigmoidf_(float v) {
    return 1.0f / (1.0f + expf(-v));
}

__device__ __forceinline__ float wred(float v) {
    #pragma unroll
    for (int off = 32; off > 0; off >>= 1) v += __shfl_xor(v, off, 64);
    return v;
}

template<bool NT>
__device__ __forceinline__ v4f ldw(const float* p) {
    if constexpr (NT)
        return __builtin_nontemporal_load(reinterpret_cast<const v4f*>(p));
    else
        return *reinterpret_cast<const v4f*>(p);
}

// CLEN must be a multiple of 256.
template<int CLEN, bool NT>
__device__ __forceinline__ void dot3(const float* __restrict__ wi,
                                     const float* __restrict__ wg,
                                     const float* __restrict__ wo,
                                     const float* __restrict__ x,
                                     int lane, float& si, float& sg, float& so) {
    si = 0.f; sg = 0.f; so = 0.f;
    #pragma unroll 4
    for (int c0 = 0; c0 < CLEN; c0 += 256) {
        const int c = c0 + lane * 4;
        const v4f xv = *reinterpret_cast<const v4f*>(x + c);
        const v4f av = ldw<NT>(wi + c);
        const v4f gv = ldw<NT>(wg + c);
        const v4f ov = ldw<NT>(wo + c);
        si += av.x * xv.x + av.y * xv.y + av.z * xv.z + av.w * xv.w;
        sg += gv.x * xv.x + gv.y * xv.y + gv.z * xv.z + gv.w * xv.w;
        so += ov.x * xv.x + ov.y * xv.y + ov.z * xv.z + ov.w * xv.w;
    }
}

__device__ __forceinline__ void epilogue(float si, float sg, float so,
                                         const float* __restrict__ bi,
                                         const float* __restrict__ bh,
                                         int j, int dh, float* __restrict__ h) {
    const float gi = si + bi[j]          + bh[j];
    const float gg = sg + bi[j + 2 * dh] + bh[j + 2 * dh];
    const float go = so + bi[j + 3 * dh] + bh[j + 3 * dh];
    const float cc = sigmoidf_(gi) * tanhf(gg);
    h[j] = sigmoidf_(go) * tanhf(cc);
}

// Block = 8 waves (512 threads). SPLIT waves cooperate on one row (column
// split, LDS combine); 8/SPLIT rows per block. Grid = R*SPLIT/8 blocks.
template<int C, int SPLIT, bool NT>
__global__ __launch_bounds__(512)
void lstm_cell_k(const float* __restrict__ w,
                 const float* __restrict__ bi,
                 const float* __restrict__ bh,
                 const float* __restrict__ x,
                 float* __restrict__ h,
                 int dh)
{
    __shared__ float red[8][3];
    const int lane = threadIdx.x & 63;
    const int wl = threadIdx.x >> 6;
    const int j = (int)blockIdx.x * (8 / SPLIT) + wl / SPLIT;
    const int part = wl % SPLIT;
    constexpr int CL = C / SPLIT;
    const int off = part * CL;

    const float* wi = w + (size_t)j * C + off;
    const float* wg = w + ((size_t)j + 2u * (size_t)dh) * C + off;
    const float* wo = w + ((size_t)j + 3u * (size_t)dh) * C + off;

    float si, sg, so;
    dot3<CL, NT>(wi, wg, wo, x + off, lane, si, sg, so);
    si = wred(si); sg = wred(sg); so = wred(so);

    if (SPLIT > 1) {
        if (lane == 0) { red[wl][0] = si; red[wl][1] = sg; red[wl][2] = so; }
        __syncthreads();
        if (part == 0 && lane == 0) {
            #pragma unroll
            for (int k = 1; k < SPLIT; ++k) {
                si += red[wl + k][0];
                sg += red[wl + k][1];
                so += red[wl + k][2];
            }
            epilogue(si, sg, so, bi, bh, j, dh, h);
        }
    } else {
        if (lane == 0) epilogue(si, sg, so, bi, bh, j, dh, h);
    }
}

// y = W@x + b. SPLIT waves per row, 8/SPLIT rows per block. Grid = R*SPLIT/8.
template<int C, int SPLIT, bool NT>
__global__ __launch_bounds__(512)
void linear_k(const float* __restrict__ w,
              const float* __restrict__ b,
              const float* __restrict__ x,
              float* __restrict__ y)
{
    __shared__ float red[8];
    const int lane = threadIdx.x & 63;
    const int wl = threadIdx.x >> 6;
    const int j = (int)blockIdx.x * (8 / SPLIT) + wl / SPLIT;
    const int part = wl % SPLIT;
    constexpr int CL = C / SPLIT;
    const int off = part * CL;

    const float* wr = w + (size_t)j * C + off;
    const float* xo = x + off;
    float s = 0.f;
    #pragma unroll 4
    for (int c0 = 0; c0 < CL; c0 += 256) {
        const int c = c0 + lane * 4;
        const v4f xv = *reinterpret_cast<const v4f*>(xo + c);
        const v4f wv = ldw<NT>(wr + c);
        s += wv.x * xv.x + wv.y * xv.y + wv.z * xv.z + wv.w * xv.w;
    }
    s = wred(s);
    if (SPLIT > 1) {
        if (lane == 0) red[wl] = s;
        __syncthreads();
        if (part == 0 && lane == 0) {
            #pragma unroll
            for (int k = 1; k < SPLIT; ++k) s += red[wl + k];
            y[j] = s + b[j];
        }
    } else {
        if (lane == 0) y[j] = s + b[j];
    }
}

extern "C" void kernel_launch(void* const* d_in, const int* in_sizes, int n_in,
                              void* d_out, int out_size, void* d_ws, size_t ws_size,
                              hipStream_t stream)
{
    const float* x        = (const float*)d_in[0];
    const float* e1l0_wih = (const float*)d_in[1];
    const float* e1l0_bih = (const float*)d_in[3];
    const float* e1l0_bhh = (const float*)d_in[4];
    const float* e1l1_wih = (const float*)d_in[5];
    const float* e1l1_bih = (const float*)d_in[7];
    const float* e1l1_bhh = (const float*)d_in[8];
    const float* e2_wih   = (const float*)d_in[9];
    const float* e2_bih   = (const float*)d_in[11];
    const float* e2_bhh   = (const float*)d_in[12];
    const float* d1l0_wih = (const float*)d_in[13];
    const float* d1l0_bih = (const float*)d_in[15];
    const float* d1l0_bhh = (const float*)d_in[16];
    const float* d1l1_wih = (const float*)d_in[17];
    const float* d1l1_bih = (const float*)d_in[19];
    const float* d1l1_bhh = (const float*)d_in[20];
    const float* d2_wih   = (const float*)d_in[21];
    const float* d2_bih   = (const float*)d_in[23];
    const float* d2_bhh   = (const float*)d_in[24];
    const float* out_w    = (const float*)d_in[25];
    const float* out_b    = (const float*)d_in[26];
    float* out = (float*)d_out;

    float* ws = (float*)d_ws;
    float* h1 = ws;           // 2048
    float* h2 = ws + 2048;    // 2048
    float* z  = ws + 4096;    // 1024
    float* h3 = ws + 5120;    // 1024
    float* h4 = ws + 6144;    // 1024
    float* h5 = ws + 7168;    // 2048

    // Encoder. e1l0 weights (100.7 MB) streamed non-temporally.
    lstm_cell_k<4096, 4, true ><<<1024, 512, 0, stream>>>(e1l0_wih, e1l0_bih, e1l0_bhh, x,  h1, 2048);
    lstm_cell_k<2048, 4, false><<<1024, 512, 0, stream>>>(e1l1_wih, e1l1_bih, e1l1_bhh, h1, h2, 2048);
    lstm_cell_k<2048, 8, false><<<1024, 512, 0, stream>>>(e2_wih,   e2_bih,   e2_bhh,   h2, z,  1024);
    // Decoder
    lstm_cell_k<1024, 4, false><<< 512, 512, 0, stream>>>(d1l0_wih, d1l0_bih, d1l0_bhh, z,  h3, 1024);
    lstm_cell_k<1024, 4, false><<< 512, 512, 0, stream>>>(d1l1_wih, d1l1_bih, d1l1_bhh, h3, h4, 1024);
    lstm_cell_k<1024, 4, false><<<1024, 512, 0, stream>>>(d2_wih,   d2_bih,   d2_bhh,   h4, h5, 2048);
    // Output projection: out_w (33.6 MB) streamed non-temporally.
    linear_k<2048, 2, true ><<<1024, 512, 0, stream>>>(out_w, out_b, h5, out);
}